// Round 9
// baseline (9076.542 us; speedup 1.0000x reference)
//
#include <hip/hip_runtime.h>
#include <stdint.h>

#define NB    64
#define NN    131072
#define NPTS  1024

typedef float v2f __attribute__((ext_vector_type(2)));
typedef unsigned long long u64;

static __device__ __forceinline__ v2f vmin2(v2f a, v2f b) {
#if __has_builtin(__builtin_elementwise_min)
    return __builtin_elementwise_min(a, b);
#else
    v2f r; r.x = fminf(a.x, b.x); r.y = fminf(a.y, b.y); return r;
#endif
}

// ---------------- inter-wg protocol (R3/R6-proven): relaxed + cold slots -----
// One u64 slot per (batch, round k, rank): [dist_bits:32 | ~idx:32].
//   u64 max == (max dist, then min idx) == jnp.argmax first-occurrence.
//   ~idx != 0, so nonzero doubles as the publish flag (slots memset to 0).
// HW LESSONS: RELAXED atomics only (R4: acquire/release at agent scope =
// cache-maintenance storm, 118x). Never reuse a spin address within a launch
// (R5: reused lines poll stale; per-round-unique slots = cold fetches from the
// coherence point). R8: no LDS-broadcast hop / wave0-only forwarding — every
// wave polls globally; but only lanes < WPB poll (sparse) to cut MALL traffic.
// ALLOCATOR LESSON (R3..R8): granted arch VGPRs never exceeded 64..128 while
// demand was ~110-170 -> AGPR shuttling bloats VALU ~1.7x. This config is
// sized so TOTAL live state fits 64 regs and launch_bounds(TPB,8) pins the
// budget: the allocator has nothing to bloat.

template <int TPB_, int MINW_, int WPB_, int RPTS_, int LPTS_, int SPTS_>
__global__ __launch_bounds__(TPB_, MINW_) void fps_kernel(
    const float* __restrict__ pos,
    const int*   __restrict__ start_p,
    int*         __restrict__ out,
    u64*         __restrict__ slots)
{
#pragma clang fp contract(off)
    constexpr int NWAVE = TPB_ / 64;
    constexpr int CHUNK = NN / WPB_;
    constexpr int PPT   = CHUNK / TPB_;
    constexpr int RPAIR = RPTS_ / 2;
    constexpr int LPAIR = LPTS_ / 2;
    constexpr int SPAIR = SPTS_ / 2;
    constexpr int WSH   = (WPB_ == 8) ? 3 : 2;
    static_assert(RPTS_ + LPTS_ + SPTS_ == PPT, "split must cover PPT");

    const int wg   = blockIdx.x;
    const int xcd  = wg & 7;            // heuristic: keep a batch's wgs on one XCD
    const int sl   = wg >> 3;
    const int b    = xcd * 8 + (sl >> WSH);
    const int r    = sl & (WPB_ - 1);
    const int t    = threadIdx.x;
    const int lane = t & 63;
    const int wv   = t >> 6;

    const float* __restrict__ P  = pos + (size_t)b * NN * 3;
    const float* __restrict__ Pc = P + (size_t)r * CHUNK * 3;
    u64* __restrict__ bslots = slots + (size_t)b * NPTS * WPB_;

    // pair-packed LDS: coords of points (2l, 2l+1) adjacent -> ds_read_b64
    __shared__ float lx[LPAIR * TPB_ * 2];
    __shared__ float ly[LPAIR * TPB_ * 2];
    __shared__ float lz[LPAIR * TPB_ * 2];
    __shared__ u64   wred[2][NWAVE];        // banked by k&1 (single-barrier loop)

    // ---- one-time staging: regs then LDS (own-thread only; no barrier) ----
    v2f rx[RPAIR], ry[RPAIR], rz[RPAIR];
#pragma unroll
    for (int p = 0; p < RPAIR; ++p) {
        const float* a = Pc + (size_t)(t + (2 * p) * TPB_) * 3;
        const float* c = a + (size_t)TPB_ * 3;
        rx[p] = (v2f){a[0], c[0]};
        ry[p] = (v2f){a[1], c[1]};
        rz[p] = (v2f){a[2], c[2]};
    }
#pragma unroll
    for (int l = 0; l < LPAIR; ++l) {
        const float* a = Pc + (size_t)(t + (RPTS_ + 2 * l) * TPB_) * 3;
        const float* c = a + (size_t)TPB_ * 3;
        const int idx = (l * TPB_ + t) * 2;
        lx[idx] = a[0]; lx[idx + 1] = c[0];
        ly[idx] = a[1]; ly[idx + 1] = c[1];
        lz[idx] = a[2]; lz[idx + 1] = c[2];
    }

    const int start = start_p[0];
    float sx = P[(size_t)start * 3 + 0];
    float sy = P[(size_t)start * 3 + 1];
    float sz = P[(size_t)start * 3 + 2];
    if (r == 0 && t == 0) out[(size_t)b * NPTS] = start;

    v2f dist[PPT / 2];
#pragma unroll
    for (int p = 0; p < PPT / 2; ++p)
        dist[p] = (v2f){__builtin_inff(), __builtin_inff()};

    const int gbase = r * CHUNK;

    for (int k = 1; k < NPTS; ++k) {
        const int bank = k & 1;
        const v2f s0 = (v2f){sx, sx}, s1 = (v2f){sy, sy}, s2 = (v2f){sz, sz};
        float best = -1.0f;
        int   bi   = 0;

        // issue streamed loads early (fixed addresses, L2-resident slice)
        v2f gx[SPAIR > 0 ? SPAIR : 1], gy[SPAIR > 0 ? SPAIR : 1],
            gz[SPAIR > 0 ? SPAIR : 1];
        if constexpr (SPTS_ > 0) {
#pragma unroll
            for (int s = 0; s < SPAIR; ++s) {
                const float* a = Pc + (size_t)(t + (RPTS_ + LPTS_ + 2 * s) * TPB_) * 3;
                const float* c = a + (size_t)TPB_ * 3;
                gx[s] = (v2f){a[0], c[0]};
                gy[s] = (v2f){a[1], c[1]};
                gz[s] = (v2f){a[2], c[2]};
            }
        }

        // exact per-op rounding: (dx*dx + dy*dy) + dz*dz, contract off;
        // ascending j preserves first-occurrence argmax tie-break
#define PAIR_STEP(DP, PX, PY, PZ, I0)                                    \
        {                                                                \
            v2f dx = (PX) - s0, dy = (PY) - s1, dz = (PZ) - s2;          \
            v2f d  = (dx * dx + dy * dy) + dz * dz;                      \
            v2f nd = vmin2(dist[DP], d);                                 \
            dist[DP] = nd;                                               \
            if (nd.x > best) { best = nd.x; bi = (I0); }                 \
            if (nd.y > best) { best = nd.y; bi = (I0) + TPB_; }          \
        }

#pragma unroll
        for (int p = 0; p < RPAIR; ++p)
            PAIR_STEP(p, rx[p], ry[p], rz[p], gbase + t + (2 * p) * TPB_);
#pragma unroll
        for (int l = 0; l < LPAIR; ++l) {
            const int idx = (l * TPB_ + t) * 2;
            v2f px = *reinterpret_cast<const v2f*>(&lx[idx]);   // ds_read_b64
            v2f py = *reinterpret_cast<const v2f*>(&ly[idx]);
            v2f pz = *reinterpret_cast<const v2f*>(&lz[idx]);
            PAIR_STEP(RPAIR + l, px, py, pz, gbase + t + (RPTS_ + 2 * l) * TPB_);
        }
        if constexpr (SPTS_ > 0) {
#pragma unroll
            for (int s = 0; s < SPAIR; ++s)
                PAIR_STEP(RPAIR + LPAIR + s, gx[s], gy[s], gz[s],
                          gbase + t + (RPTS_ + LPTS_ + 2 * s) * TPB_);
        }
#undef PAIR_STEP

        u64 pk = ((u64)__float_as_uint(best) << 32) | (unsigned)~bi;

        // 64-lane wave max-reduce
#pragma unroll
        for (int o = 32; o >= 1; o >>= 1) {
            u64 q = __shfl_xor(pk, o, 64);
            if (q > pk) pk = q;
        }
        if (lane == 0) wred[bank][wv] = pk;
        __syncthreads();

        // every wave reduces the wave-partials itself (no 2nd barrier)
        u64 v = wred[bank][lane & (NWAVE - 1)];
#pragma unroll
        for (int o = 1; o < NWAVE; o <<= 1) {
            u64 q = __shfl_xor(v, o, 64);
            if (q > v) v = q;
        }
        if (t == 0)
            __hip_atomic_store(&bslots[(size_t)k * WPB_ + r], v,
                               __ATOMIC_RELAXED, __HIP_MEMORY_SCOPE_AGENT);

        // sparse spin: only lanes < WPB_ poll (cold line, relaxed); others wait
        u64 g = 0;
        if (lane < WPB_) {
            const u64* sp = &bslots[(size_t)k * WPB_ + lane];
            for (;;) {
                g = __hip_atomic_load(sp, __ATOMIC_RELAXED, __HIP_MEMORY_SCOPE_AGENT);
                if (g) break;
                __builtin_amdgcn_s_sleep(1);
            }
        }
#pragma unroll
        for (int o = 1; o < WPB_; o <<= 1) {
            u64 q = __shfl_xor(g, o, 64);
            if (q > g) g = q;
        }
        g = __shfl(g, 0);   // lanes >= WPB_ held 0; lane 0 has the true max

        const int widx = (int)~(unsigned)g;
        if (r == 0 && t == 0) out[(size_t)b * NPTS + k] = widx;
        // uniform address across lanes: one transaction per wave, L3-hot
        sx = P[(size_t)widx * 3 + 0];
        sy = P[(size_t)widx * 3 + 1];
        sz = P[(size_t)widx * 3 + 2];
    }
}

extern "C" void kernel_launch(void* const* d_in, const int* in_sizes, int n_in,
                              void* d_out, int out_size, void* d_ws, size_t ws_size,
                              hipStream_t stream)
{
    const float* pos     = (const float*)d_in[0];
    const int*   start_p = (const int*)d_in[1];
    int*         out     = (int*)d_out;
    u64*         slots   = (u64*)d_ws;

    const size_t need8 = (size_t)NB * NPTS * 8 * sizeof(u64);   // 4 MB
    const size_t need4 = (size_t)NB * NPTS * 4 * sizeof(u64);   // 2 MB

    void* args[] = { (void*)&pos, (void*)&start_p, (void*)&out, (void*)&slots };

    if (ws_size >= need8) {
        // primary: WPB=8, 2 blocks/CU, state fits the 64-VGPR budget exactly
        hipMemsetAsync(d_ws, 0, need8, stream);
        hipError_t e = hipLaunchCooperativeKernel(
            (const void*)fps_kernel<1024, 8, 8, 8, 6, 2>,
            dim3(NB * 8), dim3(1024), args, 0, stream);
        if (e != hipSuccess)
            fps_kernel<1024, 8, 8, 8, 6, 2><<<dim3(NB * 8), dim3(1024), 0, stream>>>(
                pos, start_p, out, slots);
    } else {
        // fallback: R6-exact geometry (TPB=1024, WPB=4, 20 reg + 12 LDS)
        hipMemsetAsync(d_ws, 0, need4, stream);
        hipError_t e = hipLaunchCooperativeKernel(
            (const void*)fps_kernel<1024, 4, 4, 20, 12, 0>,
            dim3(NB * 4), dim3(1024), args, 0, stream);
        if (e != hipSuccess)
            fps_kernel<1024, 4, 4, 20, 12, 0><<<dim3(NB * 4), dim3(1024), 0, stream>>>(
                pos, start_p, out, slots);
    }
}

// Round 10
// 4002.884 us; speedup vs baseline: 2.2675x; 2.2675x over previous
//
#include <hip/hip_runtime.h>
#include <stdint.h>

#define NB    64
#define NN    131072
#define NPTS  1024
#define TPB   512                  // 8 waves, 1 block/CU -> 2 waves/SIMD -> 256-VGPR HW budget
#define WPB   4                    // workgroups per batch
#define NWAVE (TPB / 64)
#define CHUNK (NN / WPB)           // 32768 points per wg
#define PPT   (CHUNK / TPB)        // 64 points per thread
#define RPTS  40                   // register-resident points/thread (120 VGPR)
#define LPTS  24                   // LDS-resident points/thread (147456 B)
#define RPAIR (RPTS / 2)
#define LPAIR (LPTS / 2)

typedef float v2f __attribute__((ext_vector_type(2)));
typedef unsigned long long u64;

static __device__ __forceinline__ v2f vmin2(v2f a, v2f b) {
#if __has_builtin(__builtin_elementwise_min)
    return __builtin_elementwise_min(a, b);
#else
    v2f r; r.x = fminf(a.x, b.x); r.y = fminf(a.y, b.y); return r;
#endif
}

// ---------------- inter-wg protocol (R3/R6-proven): relaxed + cold slots -----
// One u64 slot per (batch, round k, rank): [dist_bits:32 | ~idx:32].
//   u64 max == (max dist, then min idx) == jnp.argmax first-occurrence.
//   ~idx != 0, so nonzero doubles as the publish flag (slots memset to 0).
// HW LESSONS: RELAXED atomics only (R4: acquire/release at agent scope =
// cache-maintenance storm, 118x). Never reuse a spin address within a launch
// (R5: reused lines poll stale). No payload words, no LDS-broadcast hop
// (R5/R8 both regressed): single-word spin + uniform P[widx] reload.
// ALLOCATOR LESSON (R3..R9): arch-VGPR grant is heuristic; overflow goes to
// AGPR-shuttle (VALU bloat ~2.4us/round) or scratch (R9, FETCH 10.7 GB).
// This config: 2 waves/SIMD (HW budget 256) + waves_per_eu(2,2) + static
// demand ~200 -> state genuinely fits arch VGPRs.

__global__ __launch_bounds__(TPB)
__attribute__((amdgpu_waves_per_eu(2, 2)))
void fps_kernel(
    const float* __restrict__ pos,
    const int*   __restrict__ start_p,
    int*         __restrict__ out,
    u64*         __restrict__ slots)
{
#pragma clang fp contract(off)
    const int wg   = blockIdx.x;
    const int xcd  = wg & 7;            // heuristic: keep a batch's 4 wgs on one XCD
    const int sl   = wg >> 3;
    const int b    = xcd * 8 + (sl >> 2);
    const int r    = sl & 3;
    const int t    = threadIdx.x;
    const int lane = t & 63;
    const int wv   = t >> 6;

    const float* __restrict__ P  = pos + (size_t)b * NN * 3;
    const float* __restrict__ Pc = P + (size_t)r * CHUNK * 3;
    u64* __restrict__ bslots = slots + (size_t)b * NPTS * WPB;

    // pair-packed LDS: coords of points (2l, 2l+1) adjacent -> ds_read_b64
    __shared__ float lx[LPAIR * TPB * 2];   // 49152 B
    __shared__ float ly[LPAIR * TPB * 2];
    __shared__ float lz[LPAIR * TPB * 2];   // 147456 B total
    __shared__ u64   wred[2][NWAVE];        // banked by k&1 (single-barrier loop)

    // ---- one-time staging: j<40 -> regs, j in [40,64) -> LDS (own-thread only) ----
    v2f rx[RPAIR], ry[RPAIR], rz[RPAIR];
#pragma unroll
    for (int p = 0; p < RPAIR; ++p) {
        const float* a = Pc + (size_t)(t + (2 * p) * TPB) * 3;
        const float* c = a + (size_t)TPB * 3;
        rx[p] = (v2f){a[0], c[0]};
        ry[p] = (v2f){a[1], c[1]};
        rz[p] = (v2f){a[2], c[2]};
    }
#pragma unroll
    for (int l = 0; l < LPAIR; ++l) {
        const float* a = Pc + (size_t)(t + (RPTS + 2 * l) * TPB) * 3;
        const float* c = a + (size_t)TPB * 3;
        const int idx = (l * TPB + t) * 2;
        lx[idx] = a[0]; lx[idx + 1] = c[0];   // same-thread RAW only: no barrier
        ly[idx] = a[1]; ly[idx + 1] = c[1];
        lz[idx] = a[2]; lz[idx + 1] = c[2];
    }

    const int start = start_p[0];
    float sx = P[(size_t)start * 3 + 0];
    float sy = P[(size_t)start * 3 + 1];
    float sz = P[(size_t)start * 3 + 2];
    if (r == 0 && t == 0) out[(size_t)b * NPTS] = start;

    v2f dist[PPT / 2];
#pragma unroll
    for (int p = 0; p < PPT / 2; ++p)
        dist[p] = (v2f){__builtin_inff(), __builtin_inff()};

    const int gbase = r * CHUNK;

    for (int k = 1; k < NPTS; ++k) {
        const int bank = k & 1;
        const v2f s0 = (v2f){sx, sx}, s1 = (v2f){sy, sy}, s2 = (v2f){sz, sz};
        float best = -1.0f;
        int   bi   = 0;

        // exact per-op rounding: (dx*dx + dy*dy) + dz*dz, contract off;
        // ascending j preserves first-occurrence argmax tie-break
#define PAIR_STEP(DP, PX, PY, PZ, I0)                                    \
        {                                                                \
            v2f dx = (PX) - s0, dy = (PY) - s1, dz = (PZ) - s2;          \
            v2f d  = (dx * dx + dy * dy) + dz * dz;                      \
            v2f nd = vmin2(dist[DP], d);                                 \
            dist[DP] = nd;                                               \
            if (nd.x > best) { best = nd.x; bi = (I0); }                 \
            if (nd.y > best) { best = nd.y; bi = (I0) + TPB; }           \
        }

#pragma unroll
        for (int p = 0; p < RPAIR; ++p)
            PAIR_STEP(p, rx[p], ry[p], rz[p], gbase + t + (2 * p) * TPB);
#pragma unroll
        for (int l = 0; l < LPAIR; ++l) {
            const int idx = (l * TPB + t) * 2;
            v2f px = *reinterpret_cast<const v2f*>(&lx[idx]);   // ds_read_b64
            v2f py = *reinterpret_cast<const v2f*>(&ly[idx]);
            v2f pz = *reinterpret_cast<const v2f*>(&lz[idx]);
            PAIR_STEP(RPAIR + l, px, py, pz, gbase + t + (RPTS + 2 * l) * TPB);
        }
#undef PAIR_STEP

        u64 pk = ((u64)__float_as_uint(best) << 32) | (unsigned)~bi;

        // 64-lane wave max-reduce
#pragma unroll
        for (int o = 32; o >= 1; o >>= 1) {
            u64 q = __shfl_xor(pk, o, 64);
            if (q > pk) pk = q;
        }
        if (lane == 0) wred[bank][wv] = pk;
        __syncthreads();

        // every wave reduces the 8 wave-partials itself (no 2nd barrier)
        u64 v = wred[bank][lane & (NWAVE - 1)];
#pragma unroll
        for (int o = 1; o < NWAVE; o <<= 1) {
            u64 q = __shfl_xor(v, o, 64);
            if (q > v) v = q;
        }
        if (t == 0)
            __hip_atomic_store(&bslots[(size_t)k * WPB + r], v,
                               __ATOMIC_RELAXED, __HIP_MEMORY_SCOPE_AGENT);

        // all lanes spin on rank (lane&3)'s slot — cold line, relaxed only
        const u64* sp = &bslots[(size_t)k * WPB + (lane & 3)];
        u64 g;
        for (;;) {
            g = __hip_atomic_load(sp, __ATOMIC_RELAXED, __HIP_MEMORY_SCOPE_AGENT);
            if (g) break;
            __builtin_amdgcn_s_sleep(1);
        }
#pragma unroll
        for (int o = 1; o <= 2; o <<= 1) {
            u64 q = __shfl_xor(g, o, 64);
            if (q > g) g = q;
        }
        const int widx = (int)~(unsigned)g;
        if (r == 0 && t == 0) out[(size_t)b * NPTS + k] = widx;
        // uniform address across lanes: one transaction per wave, L3-hot
        sx = P[(size_t)widx * 3 + 0];
        sy = P[(size_t)widx * 3 + 1];
        sz = P[(size_t)widx * 3 + 2];
    }
}

extern "C" void kernel_launch(void* const* d_in, const int* in_sizes, int n_in,
                              void* d_out, int out_size, void* d_ws, size_t ws_size,
                              hipStream_t stream)
{
    const float* pos     = (const float*)d_in[0];
    const int*   start_p = (const int*)d_in[1];
    int*         out     = (int*)d_out;
    u64*         slots   = (u64*)d_ws;

    // 64 batches x 1024 rounds x 4 ranks x 8 B = 2 MB; zeroed so nonzero == published
    hipMemsetAsync(d_ws, 0, (size_t)NB * NPTS * WPB * sizeof(u64), stream);

    void* args[] = { (void*)&pos, (void*)&start_p, (void*)&out, (void*)&slots };
    hipError_t e = hipLaunchCooperativeKernel((const void*)fps_kernel,
                                              dim3(NB * WPB), dim3(TPB),
                                              args, 0, stream);
    if (e != hipSuccess) {
        // 256 blocks of 512 thr = 1 block/CU: de-facto co-resident; same protocol.
        fps_kernel<<<dim3(NB * WPB), dim3(TPB), 0, stream>>>(pos, start_p, out, slots);
    }
}